// Round 8
// baseline (8976.728 us; speedup 1.0000x reference)
//
#include <hip/hip_runtime.h>
#include <hip/hip_bf16.h>
#include <hip/hip_fp16.h>
#include <math.h>

#define NTOK 1024
#define DMODEL 512
#define NHEAD 16
#define DHEAD 32
#define DFF 2048
#define NBINS 68
#define KIT 20
#define NEGV (-1e9f)

typedef __attribute__((ext_vector_type(8))) short bf16x8;
typedef __attribute__((ext_vector_type(4))) float f32x4;
typedef __attribute__((ext_vector_type(8))) unsigned short u16x8;

__device__ inline unsigned short f2bf(float f) {
    unsigned int u = __float_as_uint(f);
    unsigned int r = (u + 0x7fff + ((u >> 16) & 1)) >> 16;
    return (unsigned short)r;
}

__device__ inline float wave_max64(float v) {
    #pragma unroll
    for (int s = 32; s; s >>= 1) v = fmaxf(v, __shfl_xor(v, s, 64));
    return v;
}
__device__ inline float wave_sum64(float v) {
    #pragma unroll
    for (int s = 32; s; s >>= 1) v += __shfl_xor(v, s, 64);
    return v;
}

// ---------------- prep: 10 weight transposes + stats (la, g0, ctrs) + ln_mha ----------------
__global__ void prep_kernel(const float* __restrict__ w_q, const float* __restrict__ w_k,
                            const float* __restrict__ w_v, const float* __restrict__ w_g,
                            const float* __restrict__ w_o, const float* __restrict__ w_qs,
                            const float* __restrict__ w_ks, const float* __restrict__ sw1,
                            const float* __restrict__ sw3, const float* __restrict__ sw2,
                            unsigned short* __restrict__ wt_qkvg, unsigned short* __restrict__ wt_o,
                            unsigned short* __restrict__ wt_qsks, unsigned short* __restrict__ wt_13,
                            unsigned short* __restrict__ wt_2,
                            const float* __restrict__ mask, float* __restrict__ la,
                            float* __restrict__ gv, unsigned* __restrict__ ctrs,
                            const float* __restrict__ hin, const float* __restrict__ lng,
                            const float* __restrict__ lnb, unsigned short* __restrict__ hnb) {
    __shared__ float red[256];
    __shared__ float T[32][33];
    int b = blockIdx.x, tid = threadIdx.x;
    if (b == 4864) {   // stats block: la + masked g0 + barrier counters
        red[tid] = mask[tid] + mask[tid + 256] + mask[tid + 512] + mask[tid + 768];
        __syncthreads();
        for (int off = 128; off; off >>= 1) { if (tid < off) red[tid] += red[tid + off]; __syncthreads(); }
        float lognv = __logf(red[0]);
        for (int i = tid; i < NTOK; i += 256) la[i] = (mask[i] > 0.f) ? -lognv : NEGV;
        for (int i = tid; i < NHEAD * NTOK; i += 256)
            gv[i] = (mask[i & 1023] > 0.f) ? 0.f : NEGV;
        for (int i = tid; i < NHEAD * 64; i += 256) ctrs[i] = 0u;
        return;
    }
    if (b > 4864) {    // LayerNorm(h) -> bf16 hnb
        int n = b - 4865;
        const float* row = hin + (size_t)n * DMODEL;
        float a = row[tid], bb = row[tid + 256];
        red[tid] = a + bb;
        __syncthreads();
        for (int off = 128; off; off >>= 1) { if (tid < off) red[tid] += red[tid + off]; __syncthreads(); }
        float mu = red[0] * (1.0f / DMODEL);
        __syncthreads();
        float d0 = a - mu, d1 = bb - mu;
        red[tid] = d0 * d0 + d1 * d1;
        __syncthreads();
        for (int off = 128; off; off >>= 1) { if (tid < off) red[tid] += red[tid + off]; __syncthreads(); }
        float rstd = rsqrtf(red[0] * (1.0f / DMODEL) + 1e-5f);
        hnb[(size_t)n * DMODEL + tid]       = f2bf(d0 * rstd * lng[tid] + lnb[tid]);
        hnb[(size_t)n * DMODEL + tid + 256] = f2bf(d1 * rstd * lng[tid + 256] + lnb[tid + 256]);
        return;
    }
    const float* W; unsigned short* D; int K, N, t;
    if (b < 1792) {
        int which = b >> 8; t = b & 255; K = 512; N = 512;
        switch (which) {
            case 0: W = w_q;  D = wt_qkvg; break;
            case 1: W = w_k;  D = wt_qkvg + 512 * 512; break;
            case 2: W = w_v;  D = wt_qkvg + 2 * 512 * 512; break;
            case 3: W = w_g;  D = wt_qkvg + 3 * 512 * 512; break;
            case 4: W = w_o;  D = wt_o; break;
            case 5: W = w_qs; D = wt_qsks; break;
            default: W = w_ks; D = wt_qsks + 512 * 512; break;
        }
    } else if (b < 2816) { W = sw1; D = wt_13;              K = 512;  N = 2048; t = b - 1792; }
    else if (b < 3840)   { W = sw3; D = wt_13 + 2048 * 512; K = 512;  N = 2048; t = b - 2816; }
    else                 { W = sw2; D = wt_2;               K = 2048; N = 512;  t = b - 3840; }
    int nx = N >> 5;
    int n0 = (t % nx) * 32, k0 = (t / nx) * 32;
    int r = tid >> 3, c0 = (tid & 7) * 4;
    float4 v4 = *(const float4*)&W[(size_t)(k0 + r) * N + n0 + c0];
    T[r][c0] = v4.x; T[r][c0 + 1] = v4.y; T[r][c0 + 2] = v4.z; T[r][c0 + 3] = v4.w;
    __syncthreads();
    ushort4 o;
    o.x = f2bf(T[c0][r]); o.y = f2bf(T[c0 + 1][r]);
    o.z = f2bf(T[c0 + 2][r]); o.w = f2bf(T[c0 + 3][r]);
    *(ushort4*)&D[(size_t)(n0 + r) * K + k0 + c0] = o;
}

// ---------------- fused residual + LayerNorm -> h_out f32, ln_out bf16 ----------------
template<int GATED>
__global__ void res_ln_kernel(const float* __restrict__ base, const __half* __restrict__ Gh,
                              const float* __restrict__ t1, const float* __restrict__ mask,
                              const float* __restrict__ gm, const float* __restrict__ bt,
                              float* __restrict__ hout, unsigned short* __restrict__ lnout) {
    int n = blockIdx.x, tid = threadIdx.x;
    __shared__ float red[256];
    float mk = mask[n];
    size_t off = (size_t)n * DMODEL;
    float a, b;
    if (GATED) {
        float g0 = __half2float(Gh[off + tid]);
        float g1 = __half2float(Gh[off + tid + 256]);
        a = base[off + tid]       + g0 * t1[off + tid]       * mk;
        b = base[off + tid + 256] + g1 * t1[off + tid + 256] * mk;
    } else {
        a = base[off + tid]       + t1[off + tid]       * mk;
        b = base[off + tid + 256] + t1[off + tid + 256] * mk;
    }
    hout[off + tid] = a; hout[off + tid + 256] = b;
    red[tid] = a + b;
    __syncthreads();
    for (int o2 = 128; o2; o2 >>= 1) { if (tid < o2) red[tid] += red[tid + o2]; __syncthreads(); }
    float mu = red[0] * (1.0f / DMODEL);
    __syncthreads();
    float d0 = a - mu, d1 = b - mu;
    red[tid] = d0 * d0 + d1 * d1;
    __syncthreads();
    for (int o2 = 128; o2; o2 >>= 1) { if (tid < o2) red[tid] += red[tid + o2]; __syncthreads(); }
    float rstd = rsqrtf(red[0] * (1.0f / DMODEL) + 1e-5f);
    lnout[off + tid]       = f2bf(d0 * rstd * gm[tid] + bt[tid]);
    lnout[off + tid + 256] = f2bf(d1 * rstd * gm[tid + 256] + bt[tid + 256]);
}

// ---------------- MFMA GEMM (128x128 tile, BK=64) ----------------
// MODE 0: f32 C.  MODE 2: bf16 Cb, cols<N (B rows clamped).  MODE 3: fp16 Ch.
// MODE 4: QKVG epilogue -> Cb=Qp, P2=Kp, P3=Vt, Ch=sigmoid(G).
template<int MODE>
__global__ __launch_bounds__(256)
void mfma_gemm(const unsigned short* __restrict__ A, const unsigned short* __restrict__ Bt,
               float* __restrict__ C, __half* __restrict__ Ch, unsigned short* __restrict__ Cb,
               unsigned short* __restrict__ P2, unsigned short* __restrict__ P3,
               int N, int K, int lda, int ldb, int ldc,
               long sA, long sB, long sC) {
    __shared__ unsigned short As[128 * 64];
    __shared__ unsigned short Bs[128 * 64];
    int h = blockIdx.z;
    A += (size_t)h * sA; Bt += (size_t)h * sB;
    const int tid = threadIdx.x;
    const int lane = tid & 63, wid = tid >> 6;
    const int wr = wid >> 1, wc = wid & 1;
    const int lr = lane & 15, kg = lane >> 4;
    const int row0 = blockIdx.y * 128, col0 = blockIdx.x * 128;
    f32x4 acc[4][4];
    #pragma unroll
    for (int i = 0; i < 4; i++)
        #pragma unroll
        for (int j = 0; j < 4; j++) acc[i][j] = (f32x4){0.f, 0.f, 0.f, 0.f};

    for (int k0 = 0; k0 < K; k0 += 64) {
        #pragma unroll
        for (int i = 0; i < 4; i++) {
            int cid = tid + i * 256;
            int r = cid >> 3, sl = cid & 7;
            int rb = col0 + r; if (rb > N - 1) rb = N - 1;
            u16x8 va = *(const u16x8*)&A[(size_t)(row0 + r) * lda + k0 + sl * 8];
            u16x8 vb = *(const u16x8*)&Bt[(size_t)rb * ldb + k0 + sl * 8];
            *(u16x8*)&As[r * 64 + ((sl ^ (r & 7)) * 8)] = va;
            *(u16x8*)&Bs[r * 64 + ((sl ^ (r & 7)) * 8)] = vb;
        }
        __syncthreads();
        #pragma unroll
        for (int ks = 0; ks < 2; ks++) {
            bf16x8 af[4], bfr[4];
            #pragma unroll
            for (int f = 0; f < 4; f++) {
                int ra = wr * 64 + f * 16 + lr;
                af[f] = *(const bf16x8*)&As[ra * 64 + (((ks * 4 + kg) ^ (ra & 7)) * 8)];
                int rb = wc * 64 + f * 16 + lr;
                bfr[f] = *(const bf16x8*)&Bs[rb * 64 + (((ks * 4 + kg) ^ (rb & 7)) * 8)];
            }
            #pragma unroll
            for (int i = 0; i < 4; i++)
                #pragma unroll
                for (int j = 0; j < 4; j++)
                    acc[i][j] = __builtin_amdgcn_mfma_f32_16x16x32_bf16(af[i], bfr[j], acc[i][j], 0, 0, 0);
        }
        __syncthreads();
    }
    #pragma unroll
    for (int i = 0; i < 4; i++) {
        int row = row0 + wr * 64 + i * 16 + kg * 4;
        #pragma unroll
        for (int j = 0; j < 4; j++) {
            int col = col0 + wc * 64 + j * 16 + lr;
            #pragma unroll
            for (int e = 0; e < 4; e++) {
                float v = acc[i][j][e];
                if (MODE == 0) {
                    C[(size_t)h * sC + (size_t)(row + e) * ldc + col] = v;
                } else if (MODE == 2) {
                    if (col < N)
                        Cb[(size_t)h * sC + (size_t)(row + e) * ldc + col] = f2bf(v);
                } else if (MODE == 3) {
                    Ch[(size_t)h * sC + (size_t)(row + e) * ldc + col] = __float2half(v);
                } else {
                    int region = col >> 9;          // 0=Q 1=K 2=V 3=G
                    int cc = col & 511;
                    int hh = cc >> 5, kk = cc & 31;
                    if (region == 0) {
                        size_t bidx = (((size_t)hh << 10) + (row + e)) * 64 + kk;
                        Cb[bidx] = f2bf(v * 0.17677669529663687f);
                        Cb[bidx + 32] = 0;
                    } else if (region == 1) {
                        size_t bidx = (((size_t)hh << 10) + (row + e)) * 64 + kk;
                        P2[bidx] = f2bf(v);
                        P2[bidx + 32] = 0;
                    } else if (region == 2) {
                        P3[(((size_t)hh * 32 + kk) << 10) + (row + e)] = f2bf(v);
                    } else {
                        Ch[(size_t)(row + e) * 512 + cc] = __float2half(1.f / (1.f + __expf(-v)));
                    }
                }
            }
        }
    }
}

// ---------------- FFN w1/w3 dual GEMM + silu*mul epilogue -> bf16 ffb ----------------
__global__ __launch_bounds__(256)
void ffn13_gemm(const unsigned short* __restrict__ A, const unsigned short* __restrict__ B1,
                const unsigned short* __restrict__ B2, unsigned short* __restrict__ outb) {
    __shared__ unsigned short As[128 * 64];
    __shared__ unsigned short B1s[128 * 64];
    __shared__ unsigned short B2s[128 * 64];
    const int tid = threadIdx.x;
    const int lane = tid & 63, wid = tid >> 6;
    const int wr = wid >> 1, wc = wid & 1;
    const int lr = lane & 15, kg = lane >> 4;
    const int row0 = blockIdx.y * 128, col0 = blockIdx.x * 128;
    f32x4 acc1[4][4], acc2[4][4];
    #pragma unroll
    for (int i = 0; i < 4; i++)
        #pragma unroll
        for (int j = 0; j < 4; j++) { acc1[i][j] = (f32x4){0,0,0,0}; acc2[i][j] = (f32x4){0,0,0,0}; }
    for (int k0 = 0; k0 < 512; k0 += 64) {
        #pragma unroll
        for (int i = 0; i < 4; i++) {
            int cid = tid + i * 256;
            int r = cid >> 3, sl = cid & 7;
            u16x8 va = *(const u16x8*)&A[(size_t)(row0 + r) * 512 + k0 + sl * 8];
            u16x8 v1 = *(const u16x8*)&B1[(size_t)(col0 + r) * 512 + k0 + sl * 8];
            u16x8 v2 = *(const u16x8*)&B2[(size_t)(col0 + r) * 512 + k0 + sl * 8];
            *(u16x8*)&As[r * 64 + ((sl ^ (r & 7)) * 8)] = va;
            *(u16x8*)&B1s[r * 64 + ((sl ^ (r & 7)) * 8)] = v1;
            *(u16x8*)&B2s[r * 64 + ((sl ^ (r & 7)) * 8)] = v2;
        }
        __syncthreads();
        #pragma unroll
        for (int ks = 0; ks < 2; ks++) {
            bf16x8 af[4], b1f[4], b2f[4];
            #pragma unroll
            for (int f = 0; f < 4; f++) {
                int ra = wr * 64 + f * 16 + lr;
                af[f] = *(const bf16x8*)&As[ra * 64 + (((ks * 4 + kg) ^ (ra & 7)) * 8)];
                int rb = wc * 64 + f * 16 + lr;
                b1f[f] = *(const bf16x8*)&B1s[rb * 64 + (((ks * 4 + kg) ^ (rb & 7)) * 8)];
                b2f[f] = *(const bf16x8*)&B2s[rb * 64 + (((ks * 4 + kg) ^ (rb & 7)) * 8)];
            }
            #pragma unroll
            for (int i = 0; i < 4; i++)
                #pragma unroll
                for (int j = 0; j < 4; j++) {
                    acc1[i][j] = __builtin_amdgcn_mfma_f32_16x16x32_bf16(af[i], b1f[j], acc1[i][j], 0, 0, 0);
                    acc2[i][j] = __builtin_amdgcn_mfma_f32_16x16x32_bf16(af[i], b2f[j], acc2[i][j], 0, 0, 0);
                }
        }
        __syncthreads();
    }
    #pragma unroll
    for (int i = 0; i < 4; i++) {
        int row = row0 + wr * 64 + i * 16 + kg * 4;
        #pragma unroll
        for (int j = 0; j < 4; j++) {
            int col = col0 + wc * 64 + j * 16 + lr;
            #pragma unroll
            for (int e = 0; e < 4; e++) {
                float x = acc1[i][j][e], y = acc2[i][j][e];
                outb[(size_t)(row + e) * 2048 + col] = f2bf(x / (1.f + __expf(-x)) * y);
            }
        }
    }
}

// ---------------- attention: bias + mask + softmax over fp16 S; writes bf16 P in place ----
__global__ __launch_bounds__(256)
void bias_softmax_kernel(__half* __restrict__ S, const int* __restrict__ pos_bins,
                         const float* __restrict__ pos_w, const float* __restrict__ mask) {
    __shared__ int   bins_s[NTOK];
    __shared__ float pw_s[NBINS * NHEAD];
    int n = blockIdx.x, tid = threadIdx.x;
    int lane = tid & 63, wid = tid >> 6;
    #pragma unroll
    for (int i = 0; i < 4; i++) {
        int m = tid + i * 256;
        int b = pos_bins[(size_t)n * NTOK + m];
        bins_s[m] = (mask[m] > 0.f) ? b : -1;
    }
    #pragma unroll
    for (int i = 0; i < 5; i++) {
        int idx = tid + i * 256;
        if (idx < NBINS * NHEAD) pw_s[idx] = pos_w[idx];
    }
    __syncthreads();
    int mb = lane * 16;
    #pragma unroll
    for (int hh = 0; hh < 4; hh++) {
        int h = wid * 4 + hh;
        __half* row = S + ((size_t)h * NTOK + n) * NTOK;
        uint4 ua = ((const uint4*)row)[lane * 2];
        uint4 ub = ((const uint4*)row)[lane * 2 + 1];
        unsigned uu[8] = {ua.x, ua.y, ua.z, ua.w, ub.x, ub.y, ub.z, ub.w};
        float v[16];
        #pragma unroll
        for (int j = 0; j < 8; j++) {
            float2 f = __half22float2(*(__half2*)&uu[j]);
            v[2 * j] = f.x; v[2 * j + 1] = f.y;
        }
        float mx = -INFINITY;
        #pragma unroll
        for (int j = 0; j < 16; j++) {
            int b = bins_s[mb + j];
            v[j] = (b >= 0) ? v[j] + pw_s[b * NHEAD + h] : NEGV;
            mx = fmaxf(mx, v[j]);
        }
        mx = wave_max64(mx);
        float sum = 0.f;
        #pragma unroll
        for (int j = 0; j < 16; j++) { v[j] = __expf(v[j] - mx); sum += v[j]; }
        float inv = 1.f / wave_sum64(sum);
        unsigned short o[16];
        #pragma unroll
        for (int j = 0; j < 16; j++) o[j] = f2bf(v[j] * inv);
        ((uint4*)row)[lane * 2]     = *(uint4*)&o[0];
        ((uint4*)row)[lane * 2 + 1] = *(uint4*)&o[8];
    }
}

// ---------------- sinkhorn Qs/Ks: normalize + scale + compact [H][N][32] bf16 -------------
__global__ void norm_pad_kernel(const float* __restrict__ qsks, const float* __restrict__ rh,
                                const float* __restrict__ ev,
                                unsigned short* __restrict__ Qsc, unsigned short* __restrict__ Ksc) {
    int idx = blockIdx.x * 256 + threadIdx.x;   // 16384 = h*1024 + n
    int h = idx >> 10, n = idx & 1023;
    const float* q = &qsks[(size_t)n * 1024 + h * 32];
    const float* k = q + 512;
    float s = rh[h] / ev[h];
    float qv[32], kv[32];
    float ssq = 0.f, ssk = 0.f;
    #pragma unroll
    for (int d = 0; d < 32; d++) {
        qv[d] = q[d]; ssq += qv[d] * qv[d];
        kv[d] = k[d]; ssk += kv[d] * kv[d];
    }
    float iq = s / fmaxf(sqrtf(ssq), 1e-12f);
    float ik = 1.f / fmaxf(sqrtf(ssk), 1e-12f);
    size_t base = (size_t)idx * 32;
    #pragma unroll
    for (int d = 0; d < 32; d++) {
        Qsc[base + d] = f2bf(qv[d] * iq);
        Ksc[base + d] = f2bf(kv[d] * ik);
    }
}

// ---- one sinkhorn phase body: LSE rows via MFMA-recompute, fixed-base (no max) ----
__device__ __forceinline__ void sink_phase(
    const bf16x8& af, const unsigned short* __restrict__ Bcols,
    const float* __restrict__ dual, const float* __restrict__ la,
    float* __restrict__ outv, float bet, size_t hb, int row0,
    int lane, int w, int tid, float (*part)[16]) {
    const int wbase = w << 8;
    float s[4] = {0.f, 0.f, 0.f, 0.f};
    #pragma unroll
    for (int t = 0; t < 16; t++) {
        int col = wbase + t * 16 + (lane & 15);
        bf16x8 bf = *(const bf16x8*)&Bcols[(hb + col) * 32 + (lane >> 4) * 8];
        f32x4 acc = (f32x4){0.f, 0.f, 0.f, 0.f};
        acc = __builtin_amdgcn_mfma_f32_16x16x32_bf16(af, bf, acc, 0, 0, 0);
        float gcol = dual[hb + col];
        #pragma unroll
        for (int e = 0; e < 4; e++) s[e] += __expf(acc[e] + bet + gcol);
    }
    #pragma unroll
    for (int off = 1; off < 16; off <<= 1)
        #pragma unroll
        for (int e = 0; e < 4; e++) s[e] += __shfl_xor(s[e], off, 64);
    if ((lane & 15) == 0) {
        int rg = (lane >> 4) * 4;
        #pragma unroll
        for (int e = 0; e < 4; e++) part[w][rg + e] = s[e];
    }
    __syncthreads();
    if (tid < 16) {
        float tot = part[0][tid] + part[1][tid] + part[2][tid] + part[3][tid];
        outv[hb + row0 + tid] = la[row0 + tid] - __logf(fmaxf(tot, 1e-38f));
    }
}

// ---------------- persistent sinkhorn: 20x(f,g) + transport, per-head 64-block barriers ----
// grid 1024 = 4 blocks/CU (all co-resident via launch_bounds(256,4)); block b:
// head h = b>>6, rows row0 = (b&63)*16 (same row slice for f-rows, g-rows, transport).
__global__ __launch_bounds__(256, 4)
void sink_persist_kernel(const unsigned short* __restrict__ Qsc,
                         const unsigned short* __restrict__ Ksc,
                         float* __restrict__ fv, float* __restrict__ gv,
                         const float* __restrict__ la,
                         const float* __restrict__ alpha, const float* __restrict__ epsv,
                         const float* __restrict__ x_res, float* __restrict__ xc,
                         unsigned* __restrict__ ctrs) {
    __shared__ float part[4][16];
    __shared__ float part4[4][16][4];
    const int tid = threadIdx.x, lane = tid & 63, w = tid >> 6;
    const int b = blockIdx.x;
    const int h = b >> 6, row0 = (b & 63) << 4;
    const float bet = alpha[h] / epsv[h];
    const size_t hb = (size_t)h << 10;
    unsigned* ctr = ctrs + h * 64;   // 256B apart per head

    // A-fragments for my 16 rows: Q rows (f-phase, transport), K rows (g-phase)
    bf16x8 afQ = *(const bf16x8*)&Qsc[(hb + row0 + (lane & 15)) * 32 + (lane >> 4) * 8];
    bf16x8 afK = *(const bf16x8*)&Ksc[(hb + row0 + (lane & 15)) * 32 + (lane >> 4) * 8];

    unsigned phase = 0;
    auto barrier = [&]() {
        phase++;
        __threadfence();                       // publish my fv/gv writes
        __syncthreads();
        if (tid == 0) {
            __hip_atomic_fetch_add(ctr, 1u, __ATOMIC_ACQ_REL, __HIP_MEMORY_SCOPE_AGENT);
            while (__hip_atomic_load(ctr, __ATOMIC_ACQUIRE, __HIP_MEMORY_SCOPE_AGENT) < 64u * phase)
                __builtin_amdgcn_s_sleep(2);
        }
        __syncthreads();
        __threadfence();                       // invalidate L1 before reading peers' data
    };

    for (int it = 0; it < KIT; it++) {
        sink_phase(afQ, Ksc, gv, la, fv, bet, hb, row0, lane, w, tid, part);
        barrier();
        sink_phase(afK, Qsc, fv, la, gv, bet, hb, row0, lane, w, tid, part);
        barrier();
    }

    // ---- transport: xc[row,:] = softmax_col(fv[row] + S + gv[col]) @ x_res ----
    float fr[4];
    {
        float4 f4 = *(const float4*)&fv[hb + row0 + (lane >> 4) * 4];
        fr[0] = f4.x; fr[1] = f4.y; fr[2] = f4.z; fr[3] = f4.w;
    }
    const int wbase = w << 8;
    float s[4] = {0.f, 0.f, 0.f, 0.f};
    float a0[4] = {0.f, 0.f, 0.f, 0.f}, a1[4] = {0.f, 0.f, 0.f, 0.f}, a2[4] = {0.f, 0.f, 0.f, 0.f};
    #pragma unroll
    for (int t = 0; t < 16; t++) {
        int col = wbase + t * 16 + (lane & 15);
        bf16x8 bf = *(const bf16x8*)&Ksc[(hb + col) * 32 + (lane >> 4) * 8];
        f32x4 acc = (f32x4){0.f, 0.f, 0.f, 0.f};
        acc = __builtin_amdgcn_mfma_f32_16x16x32_bf16(afQ, bf, acc, 0, 0, 0);
        float gcol = gv[hb + col];
        const float* xr = x_res + col * 3;
        float x0 = xr[0], x1 = xr[1], x2 = xr[2];
        #pragma unroll
        for (int e = 0; e < 4; e++) {
            float ev = __expf(acc[e] + bet + gcol + fr[e]);
            s[e] += ev;
            a0[e] += ev * x0; a1[e] += ev * x1; a2[e] += ev * x2;
        }
    }
    #pragma unroll
    for (int off = 1; off < 16; off <<= 1)
        #pragma unroll
        for (int e = 0; e < 4; e++) {
            s[e]  += __shfl_xor(s[e],  off, 64);
            a0[e] += __shfl_xor(a0[e], off, 64);
            a1[e] += __shfl_xor(a1[e], off, 64);
            a2[e] += __shfl_xor(a2[e], off, 64);
        }
    if ((lane & 15) == 0) {
        int rg = (lane >> 4) * 4;
        #pragma unroll
        for (int e = 0; e < 4; e++) {
            part4[w][rg + e][0] = s[e];
            part4[w][rg + e][1] = a0[e];
            part4[w][rg + e][2] = a1[e];
            part4[w][rg + e][3] = a2[e];
        }
    }
    __syncthreads();
    if (tid < 16) {
        float tot = part4[0][tid][0] + part4[1][tid][0] + part4[2][tid][0] + part4[3][tid][0];
        float inv = 1.f / fmaxf(tot, 1e-38f);
        float b0 = part4[0][tid][1] + part4[1][tid][1] + part4[2][tid][1] + part4[3][tid][1];
        float b1 = part4[0][tid][2] + part4[1][tid][2] + part4[2][tid][2] + part4[3][tid][2];
        float b2 = part4[0][tid][3] + part4[1][tid][3] + part4[2][tid][3] + part4[3][tid][3];
        int row = row0 + tid;
        xc[(hb + row) * 3 + 0] = b0 * inv;
        xc[(hb + row) * 3 + 1] = b1 * inv;
        xc[(hb + row) * 3 + 2] = b2 * inv;
    }
}

// ---------------- final: gate = sigmoid(LN(h2)@wg + b); x_out = x_res + gate*disp*mask ----
__global__ void final_kernel(const float* __restrict__ h2, const float* __restrict__ x_res,
                             const float* __restrict__ mask, const float* __restrict__ gm,
                             const float* __restrict__ bt, const float* __restrict__ wg,
                             const float* __restrict__ wb, const float* __restrict__ lamraw,
                             const float* __restrict__ xc, float* __restrict__ xout) {
    int n = blockIdx.x;
    int tid = threadIdx.x;
    __shared__ float red[256];
    const float* row = h2 + (size_t)n * DMODEL;
    float a = row[tid], b = row[tid + 256];
    red[tid] = a + b;
    __syncthreads();
    for (int off = 128; off; off >>= 1) { if (tid < off) red[tid] += red[tid + off]; __syncthreads(); }
    float mu = red[0] * (1.0f / DMODEL);
    __syncthreads();
    float d0 = a - mu, d1 = b - mu;
    red[tid] = d0 * d0 + d1 * d1;
    __syncthreads();
    for (int off = 128; off; off >>= 1) { if (tid < off) red[tid] += red[tid + off]; __syncthreads(); }
    float rstd = rsqrtf(red[0] * (1.0f / DMODEL) + 1e-5f);
    __syncthreads();
    float t0 = (d0 * rstd * gm[tid] + bt[tid]) * wg[tid];
    float t1 = (d1 * rstd * gm[tid + 256] + bt[tid + 256]) * wg[tid + 256];
    red[tid] = t0 + t1;
    __syncthreads();
    for (int off = 128; off; off >>= 1) { if (tid < off) red[tid] += red[tid + off]; __syncthreads(); }
    if (tid == 0) {
        float gate = 1.f / (1.f + expf(-(red[0] + wb[0])));
        float mk = mask[n];
        #pragma unroll
        for (int c = 0; c < 3; c++) {
            float xr = x_res[n * 3 + c];
            float disp = 0.f;
            for (int h = 0; h < NHEAD; h++) {
                float lam = tanhf(lamraw[h]) * (1.f / NHEAD);
                disp += lam * (xc[((size_t)h * NTOK + n) * 3 + c] - xr);
            }
            xout[n * 3 + c] = xr + gate * disp * mk;
        }
    }
}

extern "C" void kernel_launch(void* const* d_in, const int* in_sizes, int n_in,
                              void* d_out, int out_size, void* d_ws, size_t ws_size,
                              hipStream_t stream) {
    const float* h          = (const float*)d_in[0];
    const float* x_res      = (const float*)d_in[1];
    const int*   pos_bins   = (const int*)d_in[2];
    const float* mask       = (const float*)d_in[3];
    const float* ln_mha_g   = (const float*)d_in[4];
    const float* ln_mha_b   = (const float*)d_in[5];
    const float* w_q        = (const float*)d_in[6];
    const float* w_k        = (const float*)d_in[7];
    const float* w_v        = (const float*)d_in[8];
    const float* w_g        = (const float*)d_in[9];
    const float* w_o        = (const float*)d_in[10];
    const float* pos_w      = (const float*)d_in[11];
    const float* ln_ff_g    = (const float*)d_in[12];
    const float* ln_ff_b    = (const float*)d_in[13];
    const float* sw_w1      = (const float*)d_in[14];
    const float* sw_w3      = (const float*)d_in[15];
    const float* sw_w2      = (const float*)d_in[16];
    const float* ln_sink_g  = (const float*)d_in[17];
    const float* ln_sink_b  = (const float*)d_in[18];
    const float* w_q_sink   = (const float*)d_in[19];
    const float* w_k_sink   = (const float*)d_in[20];
    const float* alpha_h    = (const float*)d_in[21];
    const float* r_h        = (const float*)d_in[22];
    const float* eps        = (const float*)d_in[23];
    const float* ln_gate_g  = (const float*)d_in[24];
    const float* ln_gate_b  = (const float*)d_in[25];
    const float* w_gate_w   = (const float*)d_in[26];
    const float* w_gate_b   = (const float*)d_in[27];
    const float* lambda_raw = (const float*)d_in[28];
    float* out = (float*)d_out;
    const size_t ND = (size_t)NTOK * DMODEL;

    // ---- workspace bump allocator (256B aligned) ----
    char* Wp = (char*)d_ws;
    auto alloc = [&](size_t bytes) { char* p = Wp; Wp += (bytes + 255) & ~(size_t)255; return p; };
    unsigned short* wt_qkvg = (unsigned short*)alloc((size_t)2048 * 512 * 2);
    unsigned short* wt_o    = (unsigned short*)alloc((size_t)512 * 512 * 2);
    unsigned short* wt_13   = (unsigned short*)alloc((size_t)4096 * 512 * 2);
    unsigned short* wt_2    = (unsigned short*)alloc((size_t)512 * 2048 * 2);
    unsigned short* wt_qsks = (unsigned short*)alloc((size_t)1024 * 512 * 2);
    unsigned short* hnb     = (unsigned short*)alloc(ND * 2);
    __half*         Gh      = (__half*)alloc(ND * 2);
    unsigned short* attb    = (unsigned short*)alloc(ND * 2);
    float*          t1      = (float*)alloc(ND * 4);
    float*          h1      = (float*)alloc(ND * 4);
    unsigned short* ffb     = (unsigned short*)alloc((size_t)1024 * 2048 * 2);
    unsigned short* Qp      = (unsigned short*)alloc((size_t)16 * 1024 * 64 * 2);
    unsigned short* Kp      = (unsigned short*)alloc((size_t)16 * 1024 * 64 * 2);
    unsigned short* Vt      = (unsigned short*)alloc((size_t)16 * 32 * 1024 * 2);
    unsigned short* Qsc     = (unsigned short*)alloc((size_t)16 * 1024 * 32 * 2);
    unsigned short* Ksc     = (unsigned short*)alloc((size_t)16 * 1024 * 32 * 2);
    float*          qsks    = (float*)alloc((size_t)1024 * 1024 * 4);
    char*           R       = alloc((size_t)32 * 1024 * 1024);
    float*          fv      = (float*)alloc((size_t)16 * 1024 * 4);
    float*          gv      = (float*)alloc((size_t)16 * 1024 * 4);
    float*          la      = (float*)alloc((size_t)1024 * 4);
    float*          xc      = (float*)alloc((size_t)16 * 1024 * 3 * 4);
    unsigned*       ctrs    = (unsigned*)alloc((size_t)16 * 64 * 4);

    __half* Sh_att = (__half*)R;   // attention fp16 S -> bf16 P (32MB)

    // ---- prep: weight transposes + stats (la, masked g0, ctrs=0) + ln_mha ----
    prep_kernel<<<5889, 256, 0, stream>>>(w_q, w_k, w_v, w_g, w_o, w_q_sink, w_k_sink,
                                          sw_w1, sw_w3, sw_w2,
                                          wt_qkvg, wt_o, wt_qsks, wt_13, wt_2,
                                          mask, la, gv, ctrs,
                                          h, ln_mha_g, ln_mha_b, hnb);

    // ---- MHA ----
    mfma_gemm<4><<<dim3(16, 8, 1), 256, 0, stream>>>(hnb, wt_qkvg, nullptr, Gh, Qp, Kp, Vt,
        2048, 512, 512, 512, 2048, 0, 0, 0);
    mfma_gemm<3><<<dim3(8, 8, 16), 256, 0, stream>>>(Qp, Kp, nullptr, Sh_att, nullptr, nullptr, nullptr,
        1024, 64, 64, 64, 1024, 65536, 65536, 1048576);
    bias_softmax_kernel<<<NTOK, 256, 0, stream>>>(Sh_att, pos_bins, pos_w, mask);
    mfma_gemm<2><<<dim3(1, 8, 16), 256, 0, stream>>>((const unsigned short*)Sh_att, Vt,
        nullptr, nullptr, attb, nullptr, nullptr,
        32, 1024, 1024, 1024, 512, 1048576, 32768, 32);
    mfma_gemm<0><<<dim3(4, 8, 1), 256, 0, stream>>>(attb, wt_o, t1, nullptr, nullptr, nullptr, nullptr,
        512, 512, 512, 512, 512, 0, 0, 0);
    res_ln_kernel<1><<<NTOK, 256, 0, stream>>>(h, Gh, t1, mask, ln_ff_g, ln_ff_b, h1, hnb);

    // ---- FFN ----
    ffn13_gemm<<<dim3(16, 8), 256, 0, stream>>>(hnb, wt_13, wt_13 + 2048 * 512, ffb);
    mfma_gemm<0><<<dim3(4, 8, 1), 256, 0, stream>>>(ffb, wt_2, t1, nullptr, nullptr, nullptr, nullptr,
        512, 2048, 2048, 2048, 512, 0, 0, 0);
    res_ln_kernel<0><<<NTOK, 256, 0, stream>>>(h1, nullptr, t1, mask, ln_sink_g, ln_sink_b, out, hnb);

    // ---- Sinkhorn setup ----
    mfma_gemm<0><<<dim3(8, 8, 1), 256, 0, stream>>>(hnb, wt_qsks, qsks, nullptr, nullptr, nullptr, nullptr,
        1024, 512, 512, 512, 1024, 0, 0, 0);
    norm_pad_kernel<<<64, 256, 0, stream>>>(qsks, r_h, eps, Qsc, Ksc);

    // ---- persistent sinkhorn (20 f/g iterations + transport, per-head barriers) ----
    sink_persist_kernel<<<1024, 256, 0, stream>>>(Qsc, Ksc, fv, gv, la,
                                                  alpha_h, eps, x_res, xc, ctrs);

    final_kernel<<<NTOK, 256, 0, stream>>>(out, x_res, mask, ln_gate_g, ln_gate_b,
                                           w_gate_w, w_gate_b, lambda_raw, xc, out + ND);
}

// Round 10
// 573.962 us; speedup vs baseline: 15.6399x; 15.6399x over previous
//
#include <hip/hip_runtime.h>
#include <hip/hip_bf16.h>
#include <hip/hip_fp16.h>
#include <math.h>

#define NTOK 1024
#define DMODEL 512
#define NHEAD 16
#define DHEAD 32
#define DFF 2048
#define NBINS 68
#define KIT 20
#define NEGV (-1e9f)

typedef __attribute__((ext_vector_type(8))) short bf16x8;
typedef __attribute__((ext_vector_type(4))) float f32x4;
typedef __attribute__((ext_vector_type(8))) unsigned short u16x8;

__device__ inline unsigned short f2bf(float f) {
    unsigned int u = __float_as_uint(f);
    unsigned int r = (u + 0x7fff + ((u >> 16) & 1)) >> 16;
    return (unsigned short)r;
}

__device__ inline float wave_max64(float v) {
    #pragma unroll
    for (int s = 32; s; s >>= 1) v = fmaxf(v, __shfl_xor(v, s, 64));
    return v;
}
__device__ inline float wave_sum64(float v) {
    #pragma unroll
    for (int s = 32; s; s >>= 1) v += __shfl_xor(v, s, 64);
    return v;
}

// ---------------- prep: 10 weight transposes + stats (la, g0) + ln_mha ----------------
__global__ void prep_kernel(const float* __restrict__ w_q, const float* __restrict__ w_k,
                            const float* __restrict__ w_v, const float* __restrict__ w_g,
                            const float* __restrict__ w_o, const float* __restrict__ w_qs,
                            const float* __restrict__ w_ks, const float* __restrict__ sw1,
                            const float* __restrict__ sw3, const float* __restrict__ sw2,
                            unsigned short* __restrict__ wt_qkvg, unsigned short* __restrict__ wt_o,
                            unsigned short* __restrict__ wt_qsks, unsigned short* __restrict__ wt_13,
                            unsigned short* __restrict__ wt_2,
                            const float* __restrict__ mask, float* __restrict__ la,
                            float* __restrict__ gv,
                            const float* __restrict__ hin, const float* __restrict__ lng,
                            const float* __restrict__ lnb, unsigned short* __restrict__ hnb) {
    __shared__ float red[256];
    __shared__ float T[32][33];
    int b = blockIdx.x, tid = threadIdx.x;
    if (b == 4864) {   // stats block: la + masked g0
        red[tid] = mask[tid] + mask[tid + 256] + mask[tid + 512] + mask[tid + 768];
        __syncthreads();
        for (int off = 128; off; off >>= 1) { if (tid < off) red[tid] += red[tid + off]; __syncthreads(); }
        float lognv = __logf(red[0]);
        for (int i = tid; i < NTOK; i += 256) la[i] = (mask[i] > 0.f) ? -lognv : NEGV;
        for (int i = tid; i < NHEAD * NTOK; i += 256)
            gv[i] = (mask[i & 1023] > 0.f) ? 0.f : NEGV;
        return;
    }
    if (b > 4864) {    // LayerNorm(h) -> bf16 hnb
        int n = b - 4865;
        const float* row = hin + (size_t)n * DMODEL;
        float a = row[tid], bb = row[tid + 256];
        red[tid] = a + bb;
        __syncthreads();
        for (int off = 128; off; off >>= 1) { if (tid < off) red[tid] += red[tid + off]; __syncthreads(); }
        float mu = red[0] * (1.0f / DMODEL);
        __syncthreads();
        float d0 = a - mu, d1 = bb - mu;
        red[tid] = d0 * d0 + d1 * d1;
        __syncthreads();
        for (int off = 128; off; off >>= 1) { if (tid < off) red[tid] += red[tid + off]; __syncthreads(); }
        float rstd = rsqrtf(red[0] * (1.0f / DMODEL) + 1e-5f);
        hnb[(size_t)n * DMODEL + tid]       = f2bf(d0 * rstd * lng[tid] + lnb[tid]);
        hnb[(size_t)n * DMODEL + tid + 256] = f2bf(d1 * rstd * lng[tid + 256] + lnb[tid + 256]);
        return;
    }
    const float* W; unsigned short* D; int K, N, t;
    if (b < 1792) {
        int which = b >> 8; t = b & 255; K = 512; N = 512;
        switch (which) {
            case 0: W = w_q;  D = wt_qkvg; break;
            case 1: W = w_k;  D = wt_qkvg + 512 * 512; break;
            case 2: W = w_v;  D = wt_qkvg + 2 * 512 * 512; break;
            case 3: W = w_g;  D = wt_qkvg + 3 * 512 * 512; break;
            case 4: W = w_o;  D = wt_o; break;
            case 5: W = w_qs; D = wt_qsks; break;
            default: W = w_ks; D = wt_qsks + 512 * 512; break;
        }
    } else if (b < 2816) { W = sw1; D = wt_13;              K = 512;  N = 2048; t = b - 1792; }
    else if (b < 3840)   { W = sw3; D = wt_13 + 2048 * 512; K = 512;  N = 2048; t = b - 2816; }
    else                 { W = sw2; D = wt_2;               K = 2048; N = 512;  t = b - 3840; }
    int nx = N >> 5;
    int n0 = (t % nx) * 32, k0 = (t / nx) * 32;
    int r = tid >> 3, c0 = (tid & 7) * 4;
    float4 v4 = *(const float4*)&W[(size_t)(k0 + r) * N + n0 + c0];
    T[r][c0] = v4.x; T[r][c0 + 1] = v4.y; T[r][c0 + 2] = v4.z; T[r][c0 + 3] = v4.w;
    __syncthreads();
    ushort4 o;
    o.x = f2bf(T[c0][r]); o.y = f2bf(T[c0 + 1][r]);
    o.z = f2bf(T[c0 + 2][r]); o.w = f2bf(T[c0 + 3][r]);
    *(ushort4*)&D[(size_t)(n0 + r) * K + k0 + c0] = o;
}

// ---------------- fused residual + LayerNorm (+ optional gate dot) ----------------
// val = base + (GATED ? sigmoid-gate : 1) * (t1a+t1b) * mask ; lnout = LN(val)*gm+bt
// GATECALC: gate[n] = sigmoid( sum( (LN*gg+gb) * wg ) + wb )
template<int GATED, int GATECALC>
__global__ void res_ln_kernel(const float* __restrict__ base, const __half* __restrict__ Gh,
                              const float* __restrict__ t1a, const float* __restrict__ t1b,
                              const float* __restrict__ mask,
                              const float* __restrict__ gm, const float* __restrict__ bt,
                              const float* __restrict__ gg, const float* __restrict__ gb,
                              const float* __restrict__ wg, const float* __restrict__ wb,
                              float* __restrict__ hout, unsigned short* __restrict__ lnout,
                              float* __restrict__ gate) {
    int n = blockIdx.x, tid = threadIdx.x;
    __shared__ float red[256];
    float mk = mask[n];
    size_t off = (size_t)n * DMODEL;
    float s0 = t1a[off + tid] + t1b[off + tid];
    float s1 = t1a[off + tid + 256] + t1b[off + tid + 256];
    float a, b;
    if (GATED) {
        float g0 = __half2float(Gh[off + tid]);
        float g1 = __half2float(Gh[off + tid + 256]);
        a = base[off + tid]       + g0 * s0 * mk;
        b = base[off + tid + 256] + g1 * s1 * mk;
    } else {
        a = base[off + tid]       + s0 * mk;
        b = base[off + tid + 256] + s1 * mk;
    }
    hout[off + tid] = a; hout[off + tid + 256] = b;
    red[tid] = a + b;
    __syncthreads();
    for (int o2 = 128; o2; o2 >>= 1) { if (tid < o2) red[tid] += red[tid + o2]; __syncthreads(); }
    float mu = red[0] * (1.0f / DMODEL);
    __syncthreads();
    float d0 = a - mu, d1 = b - mu;
    red[tid] = d0 * d0 + d1 * d1;
    __syncthreads();
    for (int o2 = 128; o2; o2 >>= 1) { if (tid < o2) red[tid] += red[tid + o2]; __syncthreads(); }
    float rstd = rsqrtf(red[0] * (1.0f / DMODEL) + 1e-5f);
    lnout[off + tid]       = f2bf(d0 * rstd * gm[tid] + bt[tid]);
    lnout[off + tid + 256] = f2bf(d1 * rstd * gm[tid + 256] + bt[tid + 256]);
    if (GATECALC) {
        float t0 = (d0 * rstd * gg[tid] + gb[tid]) * wg[tid];
        float t1v = (d1 * rstd * gg[tid + 256] + gb[tid + 256]) * wg[tid + 256];
        __syncthreads();
        red[tid] = t0 + t1v;
        __syncthreads();
        for (int o2 = 128; o2; o2 >>= 1) { if (tid < o2) red[tid] += red[tid + o2]; __syncthreads(); }
        if (tid == 0) gate[n] = 1.f / (1.f + expf(-(red[0] + wb[0])));
    }
}

// ---------------- MFMA GEMM (128x128 tile, BK=64) ----------------
// MODE 0: f32 C (grid.z = batch/K-split via sA/sB/sC offsets).
// MODE 2: bf16 Cb, cols<N (B rows clamped).  MODE 3: fp16 Ch.
// MODE 4: QKVG epilogue -> Cb=Qp, P2=Kp, P3=Vt, Ch=sigmoid(G).
// MODE 6: qs/ks epilogue -> normalize rows per head, scale Q by rh/ev, write Cb=Qsc, P2=Ksc.
template<int MODE>
__global__ __launch_bounds__(256)
void mfma_gemm(const unsigned short* __restrict__ A, const unsigned short* __restrict__ Bt,
               float* __restrict__ C, __half* __restrict__ Ch, unsigned short* __restrict__ Cb,
               unsigned short* __restrict__ P2, unsigned short* __restrict__ P3,
               int N, int K, int lda, int ldb, int ldc,
               long sA, long sB, long sC,
               const float* __restrict__ rh, const float* __restrict__ ev) {
    __shared__ unsigned short As[128 * 64];
    __shared__ unsigned short Bs[128 * 64];
    int h = blockIdx.z;
    A += (size_t)h * sA; Bt += (size_t)h * sB;
    const int tid = threadIdx.x;
    const int lane = tid & 63, wid = tid >> 6;
    const int wr = wid >> 1, wc = wid & 1;
    const int lr = lane & 15, kg = lane >> 4;
    const int row0 = blockIdx.y * 128, col0 = blockIdx.x * 128;
    f32x4 acc[4][4];
    #pragma unroll
    for (int i = 0; i < 4; i++)
        #pragma unroll
        for (int j = 0; j < 4; j++) acc[i][j] = (f32x4){0.f, 0.f, 0.f, 0.f};

    for (int k0 = 0; k0 < K; k0 += 64) {
        #pragma unroll
        for (int i = 0; i < 4; i++) {
            int cid = tid + i * 256;
            int r = cid >> 3, sl = cid & 7;
            int rb = col0 + r; if (rb > N - 1) rb = N - 1;
            u16x8 va = *(const u16x8*)&A[(size_t)(row0 + r) * lda + k0 + sl * 8];
            u16x8 vb = *(const u16x8*)&Bt[(size_t)rb * ldb + k0 + sl * 8];
            *(u16x8*)&As[r * 64 + ((sl ^ (r & 7)) * 8)] = va;
            *(u16x8*)&Bs[r * 64 + ((sl ^ (r & 7)) * 8)] = vb;
        }
        __syncthreads();
        #pragma unroll
        for (int ks = 0; ks < 2; ks++) {
            bf16x8 af[4], bfr[4];
            #pragma unroll
            for (int f = 0; f < 4; f++) {
                int ra = wr * 64 + f * 16 + lr;
                af[f] = *(const bf16x8*)&As[ra * 64 + (((ks * 4 + kg) ^ (ra & 7)) * 8)];
                int rb = wc * 64 + f * 16 + lr;
                bfr[f] = *(const bf16x8*)&Bs[rb * 64 + (((ks * 4 + kg) ^ (rb & 7)) * 8)];
            }
            #pragma unroll
            for (int i = 0; i < 4; i++)
                #pragma unroll
                for (int j = 0; j < 4; j++)
                    acc[i][j] = __builtin_amdgcn_mfma_f32_16x16x32_bf16(af[i], bfr[j], acc[i][j], 0, 0, 0);
        }
        __syncthreads();
    }
    if (MODE == 6) {
        #pragma unroll
        for (int i = 0; i < 4; i++) {
            int row = row0 + wr * 64 + i * 16 + kg * 4;
            #pragma unroll
            for (int jp = 0; jp < 2; jp++) {
                int j0 = jp * 2, j1 = j0 + 1;
                int colbase = col0 + wc * 64 + j0 * 16;
                bool isQ = colbase < 512;
                int hh = (colbase & 511) >> 5;
                float ss[4];
                #pragma unroll
                for (int e = 0; e < 4; e++) {
                    float v0 = acc[i][j0][e], v1 = acc[i][j1][e];
                    float t = v0 * v0 + v1 * v1;
                    t += __shfl_xor(t, 1, 64);
                    t += __shfl_xor(t, 2, 64);
                    t += __shfl_xor(t, 4, 64);
                    t += __shfl_xor(t, 8, 64);
                    ss[e] = t;
                }
                float sc = isQ ? (rh[hh] / ev[hh]) : 1.f;
                unsigned short* D = isQ ? Cb : P2;
                #pragma unroll
                for (int e = 0; e < 4; e++) {
                    float inv = sc / fmaxf(sqrtf(ss[e]), 1e-12f);
                    size_t rbase = (((size_t)hh << 10) + row + e) * 32;
                    D[rbase + lr]      = f2bf(acc[i][j0][e] * inv);
                    D[rbase + 16 + lr] = f2bf(acc[i][j1][e] * inv);
                }
            }
        }
        return;
    }
    #pragma unroll
    for (int i = 0; i < 4; i++) {
        int row = row0 + wr * 64 + i * 16 + kg * 4;
        #pragma unroll
        for (int j = 0; j < 4; j++) {
            int col = col0 + wc * 64 + j * 16 + lr;
            #pragma unroll
            for (int e = 0; e < 4; e++) {
                float v = acc[i][j][e];
                if (MODE == 0) {
                    C[(size_t)h * sC + (size_t)(row + e) * ldc + col] = v;
                } else if (MODE == 2) {
                    if (col < N)
                        Cb[(size_t)h * sC + (size_t)(row + e) * ldc + col] = f2bf(v);
                } else if (MODE == 3) {
                    Ch[(size_t)h * sC + (size_t)(row + e) * ldc + col] = __float2half(v);
                } else {
                    int region = col >> 9;          // 0=Q 1=K 2=V 3=G
                    int cc = col & 511;
                    int hh = cc >> 5, kk = cc & 31;
                    if (region == 0) {
                        size_t bidx = (((size_t)hh << 10) + (row + e)) * 64 + kk;
                        Cb[bidx] = f2bf(v * 0.17677669529663687f);
                        Cb[bidx + 32] = 0;
                    } else if (region == 1) {
                        size_t bidx = (((size_t)hh << 10) + (row + e)) * 64 + kk;
                        P2[bidx] = f2bf(v);
                        P2[bidx + 32] = 0;
                    } else if (region == 2) {
                        P3[(((size_t)hh * 32 + kk) << 10) + (row + e)] = f2bf(v);
                    } else {
                        Ch[(size_t)(row + e) * 512 + cc] = __float2half(1.f / (1.f + __expf(-v)));
                    }
                }
            }
        }
    }
}

// ---------------- FFN w1/w3 dual GEMM + silu*mul epilogue -> bf16 ffb ----------------
__global__ __launch_bounds__(256)
void ffn13_gemm(const unsigned short* __restrict__ A, const unsigned short* __restrict__ B1,
                const unsigned short* __restrict__ B2, unsigned short* __restrict__ outb) {
    __shared__ unsigned short As[128 * 64];
    __shared__ unsigned short B1s[128 * 64];
    __shared__ unsigned short B2s[128 * 64];
    const int tid = threadIdx.x;
    const int lane = tid & 63, wid = tid >> 6;
    const int wr = wid >> 1, wc = wid & 1;
    const int lr = lane & 15, kg = lane >> 4;
    const int row0 = blockIdx.y * 128, col0 = blockIdx.x * 128;
    f32x4 acc1[4][4], acc2[4][4];
    #pragma unroll
    for (int i = 0; i < 4; i++)
        #pragma unroll
        for (int j = 0; j < 4; j++) { acc1[i][j] = (f32x4){0,0,0,0}; acc2[i][j] = (f32x4){0,0,0,0}; }
    for (int k0 = 0; k0 < 512; k0 += 64) {
        #pragma unroll
        for (int i = 0; i < 4; i++) {
            int cid = tid + i * 256;
            int r = cid >> 3, sl = cid & 7;
            u16x8 va = *(const u16x8*)&A[(size_t)(row0 + r) * 512 + k0 + sl * 8];
            u16x8 v1 = *(const u16x8*)&B1[(size_t)(col0 + r) * 512 + k0 + sl * 8];
            u16x8 v2 = *(const u16x8*)&B2[(size_t)(col0 + r) * 512 + k0 + sl * 8];
            *(u16x8*)&As[r * 64 + ((sl ^ (r & 7)) * 8)] = va;
            *(u16x8*)&B1s[r * 64 + ((sl ^ (r & 7)) * 8)] = v1;
            *(u16x8*)&B2s[r * 64 + ((sl ^ (r & 7)) * 8)] = v2;
        }
        __syncthreads();
        #pragma unroll
        for (int ks = 0; ks < 2; ks++) {
            bf16x8 af[4], b1f[4], b2f[4];
            #pragma unroll
            for (int f = 0; f < 4; f++) {
                int ra = wr * 64 + f * 16 + lr;
                af[f] = *(const bf16x8*)&As[ra * 64 + (((ks * 4 + kg) ^ (ra & 7)) * 8)];
                int rb = wc * 64 + f * 16 + lr;
                b1f[f] = *(const bf16x8*)&B1s[rb * 64 + (((ks * 4 + kg) ^ (rb & 7)) * 8)];
                b2f[f] = *(const bf16x8*)&B2s[rb * 64 + (((ks * 4 + kg) ^ (rb & 7)) * 8)];
            }
            #pragma unroll
            for (int i = 0; i < 4; i++)
                #pragma unroll
                for (int j = 0; j < 4; j++) {
                    acc1[i][j] = __builtin_amdgcn_mfma_f32_16x16x32_bf16(af[i], b1f[j], acc1[i][j], 0, 0, 0);
                    acc2[i][j] = __builtin_amdgcn_mfma_f32_16x16x32_bf16(af[i], b2f[j], acc2[i][j], 0, 0, 0);
                }
        }
        __syncthreads();
    }
    #pragma unroll
    for (int i = 0; i < 4; i++) {
        int row = row0 + wr * 64 + i * 16 + kg * 4;
        #pragma unroll
        for (int j = 0; j < 4; j++) {
            int col = col0 + wc * 64 + j * 16 + lr;
            #pragma unroll
            for (int e = 0; e < 4; e++) {
                float x = acc1[i][j][e], y = acc2[i][j][e];
                outb[(size_t)(row + e) * 2048 + col] = f2bf(x / (1.f + __expf(-x)) * y);
            }
        }
    }
}

// ---------------- attention: bias + mask + softmax over fp16 S; writes bf16 P in place ----
__global__ __launch_bounds__(256)
void bias_softmax_kernel(__half* __restrict__ S, const int* __restrict__ pos_bins,
                         const float* __restrict__ pos_w, const float* __restrict__ mask) {
    __shared__ int   bins_s[NTOK];
    __shared__ float pw_s[NBINS * NHEAD];
    int n = blockIdx.x, tid = threadIdx.x;
    int lane = tid & 63, wid = tid >> 6;
    #pragma unroll
    for (int i = 0; i < 4; i++) {
        int m = tid + i * 256;
        int b = pos_bins[(size_t)n * NTOK + m];
        bins_s[m] = (mask[m] > 0.f) ? b : -1;
    }
    #pragma unroll
    for (int i = 0; i < 5; i++) {
        int idx = tid + i * 256;
        if (idx < NBINS * NHEAD) pw_s[idx] = pos_w[idx];
    }
    __syncthreads();
    int mb = lane * 16;
    #pragma unroll
    for (int hh = 0; hh < 4; hh++) {
        int h = wid * 4 + hh;
        __half* row = S + ((size_t)h * NTOK + n) * NTOK;
        uint4 ua = ((const uint4*)row)[lane * 2];
        uint4 ub = ((const uint4*)row)[lane * 2 + 1];
        unsigned uu[8] = {ua.x, ua.y, ua.z, ua.w, ub.x, ub.y, ub.z, ub.w};
        float v[16];
        #pragma unroll
        for (int j = 0; j < 8; j++) {
            float2 f = __half22float2(*(__half2*)&uu[j]);
            v[2 * j] = f.x; v[2 * j + 1] = f.y;
        }
        float mx = -INFINITY;
        #pragma unroll
        for (int j = 0; j < 16; j++) {
            int b = bins_s[mb + j];
            v[j] = (b >= 0) ? v[j] + pw_s[b * NHEAD + h] : NEGV;
            mx = fmaxf(mx, v[j]);
        }
        mx = wave_max64(mx);
        float sum = 0.f;
        #pragma unroll
        for (int j = 0; j < 16; j++) { v[j] = __expf(v[j] - mx); sum += v[j]; }
        float inv = 1.f / wave_sum64(sum);
        unsigned short o[16];
        #pragma unroll
        for (int j = 0; j < 16; j++) o[j] = f2bf(v[j] * inv);
        ((uint4*)row)[lane * 2]     = *(uint4*)&o[0];
        ((uint4*)row)[lane * 2 + 1] = *(uint4*)&o[8];
    }
}

// ---------------- fused sinkhorn pass: recompute S tiles via MFMA, fixed-base LSE --------
template<int TRANSPORT>
__global__ __launch_bounds__(256)
void sink_fused_kernel(const unsigned short* __restrict__ Arows,
                       const unsigned short* __restrict__ Bcols,
                       const float* __restrict__ dual, const float* __restrict__ frow,
                       const float* __restrict__ la,
                       const float* __restrict__ alpha, const float* __restrict__ epsv,
                       const float* __restrict__ x_res,
                       float* __restrict__ outv, float* __restrict__ xc) {
    __shared__ float part[4][16][4];
    const int tid = threadIdx.x, lane = tid & 63, w = tid >> 6;
    const int b = blockIdx.x;
    const int h = b >> 6, row0 = (b & 63) << 4;
    const float bet = alpha[h] / epsv[h];
    const size_t hb = (size_t)h << 10;
    bf16x8 af = *(const bf16x8*)&Arows[(hb + row0 + (lane & 15)) * 32 + (lane >> 4) * 8];
    float fr[4];
    if (TRANSPORT) {
        float4 f4 = *(const float4*)&frow[hb + row0 + (lane >> 4) * 4];
        fr[0] = f4.x; fr[1] = f4.y; fr[2] = f4.z; fr[3] = f4.w;
    }
    const int wbase = w << 8;
    float s[4] = {0.f, 0.f, 0.f, 0.f};
    float a0[4] = {0.f, 0.f, 0.f, 0.f}, a1[4] = {0.f, 0.f, 0.f, 0.f}, a2[4] = {0.f, 0.f, 0.f, 0.f};
    #pragma unroll
    for (int t = 0; t < 16; t++) {
        int col = wbase + t * 16 + (lane & 15);
        bf16x8 bf = *(const bf16x8*)&Bcols[(hb + col) * 32 + (lane >> 4) * 8];
        f32x4 acc = (f32x4){0.f, 0.f, 0.f, 0.f};
        acc = __builtin_amdgcn_mfma_f32_16x16x32_bf16(af, bf, acc, 0, 0, 0);
        float gcol = dual[hb + col];
        float x0, x1, x2;
        if (TRANSPORT) {
            const float* xr = x_res + col * 3;
            x0 = xr[0]; x1 = xr[1]; x2 = xr[2];
        }
        #pragma unroll
        for (int e = 0; e < 4; e++) {
            float v = acc[e] + bet + gcol;
            if (TRANSPORT) v += fr[e];
            float ev = __expf(v);
            s[e] += ev;
            if (TRANSPORT) { a0[e] += ev * x0; a1[e] += ev * x1; a2[e] += ev * x2; }
        }
    }
    #pragma unroll
    for (int off = 1; off < 16; off <<= 1) {
        #pragma unroll
        for (int e = 0; e < 4; e++) {
            s[e] += __shfl_xor(s[e], off, 64);
            if (TRANSPORT) {
                a0[e] += __shfl_xor(a0[e], off, 64);
                a1[e] += __shfl_xor(a1[e], off, 64);
                a2[e] += __shfl_xor(a2[e], off, 64);
            }
        }
    }
    if ((lane & 15) == 0) {
        int rg = (lane >> 4) * 4;
        #pragma unroll
        for (int e = 0; e < 4; e++) {
            part[w][rg + e][0] = s[e];
            if (TRANSPORT) {
                part[w][rg + e][1] = a0[e];
                part[w][rg + e][2] = a1[e];
                part[w][rg + e][3] = a2[e];
            }
        }
    }
    __syncthreads();
    if (tid < 16) {
        float tot = part[0][tid][0] + part[1][tid][0] + part[2][tid][0] + part[3][tid][0];
        int row = row0 + tid;
        if (!TRANSPORT) {
            outv[hb + row] = la[row] - __logf(fmaxf(tot, 1e-38f));
        } else {
            float inv = 1.f / fmaxf(tot, 1e-38f);
            float b0 = part[0][tid][1] + part[1][tid][1] + part[2][tid][1] + part[3][tid][1];
            float b1 = part[0][tid][2] + part[1][tid][2] + part[2][tid][2] + part[3][tid][2];
            float b2 = part[0][tid][3] + part[1][tid][3] + part[2][tid][3] + part[3][tid][3];
            xc[(hb + row) * 3 + 0] = b0 * inv;
            xc[(hb + row) * 3 + 1] = b1 * inv;
            xc[(hb + row) * 3 + 2] = b2 * inv;
        }
    }
}

// ---------------- final: x_out = x_res + gate*disp*mask (gate precomputed) ----------------
__global__ void final_kernel(const float* __restrict__ x_res, const float* __restrict__ mask,
                             const float* __restrict__ lamraw, const float* __restrict__ gate,
                             const float* __restrict__ xc, float* __restrict__ xout) {
    __shared__ float lam[NHEAD];
    int tid = threadIdx.x;
    if (tid < NHEAD) lam[tid] = tanhf(lamraw[tid]) * (1.f / NHEAD);
    __syncthreads();
    int n = blockIdx.x * 256 + tid;
    float g = gate[n] * mask[n];
    #pragma unroll
    for (int c = 0; c < 3; c++) {
        float xr = x_res[n * 3 + c];
        float disp = 0.f;
        #pragma unroll
        for (int h = 0; h < NHEAD; h++)
            disp += lam[h] * (xc[(((size_t)h << 10) + n) * 3 + c] - xr);
        xout[n * 3 + c] = xr + g * disp;
    }
}

extern "C" void kernel_launch(void* const* d_in, const int* in_sizes, int n_in,
                              void* d_out, int out_size, void* d_ws, size_t ws_size,
                              hipStream_t stream) {
    const float* h          = (const float*)d_in[0];
    const float* x_res      = (const float*)d_in[1];
    const int*   pos_bins   = (const int*)d_in[2];
    const float* mask       = (const float*)d_in[3];
    const float* ln_mha_g   = (const float*)d_in[4];
    const float* ln_mha_b   = (const float*)d_in[5];
    const float* w_q        = (const float*)d_in[6];
    const float* w_k        = (const float*)d_in[7];
    const float* w_v        = (const float*)d_in[8];
    const float* w_g        = (const float*)d_in[9];
    const float* w_o        = (const float*)d_in[10];
    const float* pos_w      = (const float*)d_in[11];
    const float* ln_ff_g    = (const float*)d_in[12];
    const float* ln_ff_b    = (const float*)d_in[13];
    const float* sw_w1      = (const float*)d_in[14];
    const float* sw_w3      = (const float*)d_in[15];
    const float* sw_w2      = (const float*)d_in[16];
    const float* ln_sink_g  = (const float*)d_in[17];
    const float* ln_sink_b  = (const float*)d_in[18];
    const float* w_q_sink   = (const float*)d_in[19];
    const float* w_k_sink   = (const float*)d_in[20];
    const float* alpha_h    = (const float*)d_in[21];
    const float* r_h        = (const float*)d_in[22];
    const float* eps        = (const float*)d_in[23];
    const float* ln_gate_g  = (const float*)d_in[24];
    const float* ln_gate_b  = (const float*)d_in[25];
    const float* w_gate_w   = (const float*)d_in[26];
    const float* w_gate_b   = (const float*)d_in[27];
    const float* lambda_raw = (const float*)d_in[28];
    float* out = (float*)d_out;
    const size_t ND = (size_t)NTOK * DMODEL;

    // ---- workspace bump allocator (256B aligned) ----
    char* Wp = (char*)d_ws;
    auto alloc = [&](size_t bytes) { char* p = Wp; Wp += (bytes + 255) & ~(size_t)255; return p; };
    unsigned short* wt_qkvg = (unsigned short*)alloc((size_t)2048 * 512 * 2);
    unsigned short* wt_o    = (unsigned short*)alloc((size_t)512 * 512 * 2);
    unsigned short* wt_13   = (unsigned short*)alloc((size_t)4096 * 512 * 2);
    unsigned short* wt_2    = (unsigned short*)alloc((size_t)512 * 2048 * 2);
    unsigned short* wt_qsks = (unsigned short*)alloc((size_t)1024 * 512 * 2);
    unsigned short* hnb     = (unsigned short*)alloc(ND * 2);
    __half*         Gh      = (__half*)alloc(ND * 2);
    unsigned short* attb    = (unsigned short*)alloc(ND * 2);
    float*          t1      = (float*)alloc(ND * 4 * 2);     // two K-split halves
    float*          h1      = (float*)alloc(ND * 4);
    unsigned short* ffb     = (unsigned short*)alloc((size_t)1024 * 2048 * 2);
    unsigned short* Qp      = (unsigned short*)alloc((size_t)16 * 1024 * 64 * 2);
    unsigned short* Kp      = (unsigned short*)alloc((size_t)16 * 1024 * 64 * 2);
    unsigned short* Vt      = (unsigned short*)alloc((size_t)16 * 32 * 1024 * 2);
    unsigned short* Qsc     = (unsigned short*)alloc((size_t)16 * 1024 * 32 * 2);
    unsigned short* Ksc     = (unsigned short*)alloc((size_t)16 * 1024 * 32 * 2);
    char*           R       = alloc((size_t)32 * 1024 * 1024);
    float*          fv      = (float*)alloc((size_t)16 * 1024 * 4);
    float*          gv      = (float*)alloc((size_t)16 * 1024 * 4);
    float*          la      = (float*)alloc((size_t)1024 * 4);
    float*          xc      = (float*)alloc((size_t)16 * 1024 * 3 * 4);
    float*          gate    = (float*)alloc((size_t)1024 * 4);

    __half* Sh_att = (__half*)R;   // attention fp16 S -> bf16 P (32MB)

    // ---- prep: weight transposes + stats (la, masked g0) + ln_mha ----
    prep_kernel<<<5889, 256, 0, stream>>>(w_q, w_k, w_v, w_g, w_o, w_q_sink, w_k_sink,
                                          sw_w1, sw_w3, sw_w2,
                                          wt_qkvg, wt_o, wt_qsks, wt_13, wt_2,
                                          mask, la, gv,
                                          h, ln_mha_g, ln_mha_b, hnb);

    // ---- MHA ----
    mfma_gemm<4><<<dim3(16, 8, 1), 256, 0, stream>>>(hnb, wt_qkvg, nullptr, Gh, Qp, Kp, Vt,
        2048, 512, 512, 512, 2048, 0, 0, 0, nullptr, nullptr);
    mfma_gemm<3><<<dim3(8, 8, 16), 256, 0, stream>>>(Qp, Kp, nullptr, Sh_att, nullptr, nullptr, nullptr,
        1024, 64, 64, 64, 1024, 65536, 65536, 1048576, nullptr, nullptr);
    bias_softmax_kernel<<<NTOK, 256, 0, stream>>>(Sh_att, pos_bins, pos_w, mask);
    mfma_gemm<2><<<dim3(1, 8, 16), 256, 0, stream>>>((const unsigned short*)Sh_att, Vt,
        nullptr, nullptr, attb, nullptr, nullptr,
        32, 1024, 1024, 1024, 512, 1048576, 32768, 32, nullptr, nullptr);
    // w_o GEMM, split-K2: z in {0,1} computes K-half into t1 + z*ND
    mfma_gemm<0><<<dim3(4, 8, 2), 256, 0, stream>>>(attb, wt_o, t1, nullptr, nullptr, nullptr, nullptr,
        512, 256, 512, 512, 512, 256, 256, (long)ND, nullptr, nullptr);
    res_ln_kernel<1, 0><<<NTOK, 256, 0, stream>>>(h, Gh, t1, t1 + ND, mask, ln_ff_g, ln_ff_b,
        nullptr, nullptr, nullptr, nullptr, h1, hnb, nullptr);

    // ---- FFN ----
    ffn13_gemm<<<dim3(16, 8), 256, 0, stream>>>(hnb, wt_13, wt_13 + 2048 * 512, ffb);
    // w2 GEMM, split-K2 over K=2048
    mfma_gemm<0><<<dim3(4, 8, 2), 256, 0, stream>>>(ffb, wt_2, t1, nullptr, nullptr, nullptr, nullptr,
        512, 1024, 2048, 2048, 512, 1024, 1024, (long)ND, nullptr, nullptr);
    res_ln_kernel<0, 1><<<NTOK, 256, 0, stream>>>(h1, nullptr, t1, t1 + ND, mask, ln_sink_g, ln_sink_b,
        ln_gate_g, ln_gate_b, w_gate_w, w_gate_b, out, hnb, gate);

    // ---- Sinkhorn setup: qs/ks GEMM with fused normalize+scale epilogue ----
    mfma_gemm<6><<<dim3(8, 8, 1), 256, 0, stream>>>(hnb, wt_qsks, nullptr, nullptr, Qsc, Ksc, nullptr,
        1024, 512, 512, 512, 1024, 0, 0, 0, r_h, eps);

    // ---- sinkhorn iterations: recompute S via MFMA each pass ----
    for (int it = 0; it < KIT; it++) {
        sink_fused_kernel<0><<<1024, 256, 0, stream>>>(Qsc, Ksc, gv, nullptr, la,
                                                       alpha_h, eps, nullptr, fv, nullptr);
        sink_fused_kernel<0><<<1024, 256, 0, stream>>>(Ksc, Qsc, fv, nullptr, la,
                                                       alpha_h, eps, nullptr, gv, nullptr);
    }
    sink_fused_kernel<1><<<1024, 256, 0, stream>>>(Qsc, Ksc, gv, fv, la,
                                                   alpha_h, eps, x_res, nullptr, xc);

    final_kernel<<<4, 256, 0, stream>>>(x_res, mask, lambda_raw, gate, xc, out + ND);
}